// Round 7
// baseline (255.592 us; speedup 1.0000x reference)
//
#include <hip/hip_runtime.h>
#include <hip/hip_bf16.h>

#define BB 4
#define HH 8
#define NN 4096
#define DD 64
#define RR 256

constexpr float SCALE = 0.35355339059327373f;  // 64^(-1/4)
constexpr float KEPS  = 0.001f;

typedef __attribute__((ext_vector_type(8)))  short short8;   // MFMA A/B frag
typedef __attribute__((ext_vector_type(16))) float f32x16;   // 32x32 MFMA C/D

#define MFMA(a, b, c) __builtin_amdgcn_mfma_f32_32x32x16_bf16(a, b, c, 0, 0, 0)

union S8U { short8 s; uint4 u; };

__device__ inline unsigned bfpk(float a, float b) {          // fp32x2 -> bf16x2 RTNE
    __hip_bfloat162 h = __float22bfloat162_rn(make_float2(a, b));
    return *reinterpret_cast<unsigned*>(&h);
}
__device__ inline f32x16 fz16() {
    f32x16 z;
#pragma unroll
    for (int e = 0; e < 16; ++e) z[e] = 0.f;
    return z;
}

// ---------------------------------------------------------------------------
// prep: projb = bf16(proj * SCALE)  row-major [256][64]  (32 KB, L1/L2-resident)
// ---------------------------------------------------------------------------
__global__ __launch_bounds__(256)
void prep_proj(const float* __restrict__ proj, unsigned short* __restrict__ projb)
{
    const int i = (blockIdx.x * 256 + threadIdx.x) * 4;
    const float4 v = *(const float4*)(proj + i);
    uint2 o; o.x = bfpk(v.x * SCALE, v.y * SCALE); o.y = bfpk(v.z * SCALE, v.w * SCALE);
    *(uint2*)(projb + i) = o;
}

// ---------------------------------------------------------------------------
// Kernel 1: per (bh, n-chunk 256, r-half 128): double-buffered LDS staging.
//   kt[n][d]  (stride 68, K*m bf16)  -> GEMM1 A-frags, 2xb64, <=2-way banks
//   vt[d][n]  (stride 36, V^T*m bf16)-> GEMM2 A-frags, 2xb64, <=2-way banks
//   V staged COLUMN-wise from global (coalesced dword/wave) -> transposed write.
//   GEMM1: phi = relu(Km . projS^T) + eps    C col = r (32 r per wave)
//   register half-swap (shfl_xor 32): C-regs -> B-operand frags (k=n)
//   GEMM2: ctxT[d][r] += V^T . phi
// MFMA 32x32x16: A[m=l31][k=hf*8+j], B[k=hf*8+j][col=l31],
//                C col=l31, row=(i&3)+8*(i>>2)+4*hf.
// grid (32, HH, BB) = 1024 blocks; lb(256,3).
// ---------------------------------------------------------------------------
__global__ __launch_bounds__(256, 3)
void pk_ctx_kernel(const float* __restrict__ Kmat, const float* __restrict__ Vmat,
                   const float* __restrict__ mask, const unsigned short* __restrict__ projb,
                   float* __restrict__ g_ctxT, float* __restrict__ g_ksum)
{
    __shared__ __align__(16) unsigned short kt[2][32 * 68];   // 8.5 KB
    __shared__ __align__(16) unsigned short vt[2][64 * 36];   // 9 KB

    const int tid = threadIdx.x;
    const int w = tid >> 6, lane = tid & 63;
    const int l31 = lane & 31, hf = lane >> 5;
    const int b = blockIdx.z, h = blockIdx.y;
    const int bh = b * HH + h;
    const int nc = blockIdx.x >> 1, rhalf = blockIdx.x & 1;
    const int n0 = nc * 256;
    const int rg = rhalf * 128 + w * 32 + l31;         // this lane's r

    // K staging coords (row-major)
    const int sn = tid >> 3, sc = (tid & 7) * 8;
    const long krow = ((long)bh * NN + n0 + sn) * DD + sc;
    const int  mrow = b * NN + n0 + sn;
    // V staging coords (column load, transposed store)
    const int dcol = tid & 63, ngrp = tid >> 6;
    const long vcol = ((long)bh * NN + n0 + ngrp * 8) * DD + dcol;
    const int  mgrp = b * NN + n0 + ngrp * 8;

    // resident proj B-frags for this wave's 32 r
    short8 pfrag[4];
#pragma unroll
    for (int ks = 0; ks < 4; ++ks)
        pfrag[ks] = *(const short8*)(projb + rg * DD + ks * 16 + hf * 8);

    f32x16 acc[2];          // [mt = d-half], col = r
    acc[0] = fz16(); acc[1] = fz16();
    float ksum = 0.f;

    auto stage = [&](int buf, int sub) {
        // ---- K*m row-major ----
        const long koff = krow + (long)sub * 32 * DD;
        const float m = mask[mrow + sub * 32];
        const float4 ka = *(const float4*)(Kmat + koff);
        const float4 kc = *(const float4*)(Kmat + koff + 4);
        *(uint2*)&kt[buf][sn * 68 + sc] =
            make_uint2(bfpk(ka.x * m, ka.y * m), bfpk(ka.z * m, ka.w * m));
        *(uint2*)&kt[buf][sn * 68 + sc + 4] =
            make_uint2(bfpk(kc.x * m, kc.y * m), bfpk(kc.z * m, kc.w * m));
        // ---- V^T*m: column load (coalesced over lanes), transposed store ----
        const long voff = vcol + (long)sub * 32 * DD;
        float vv[8];
#pragma unroll
        for (int j = 0; j < 8; ++j) vv[j] = Vmat[voff + (long)j * DD];
        const float4 ma = *(const float4*)(mask + mgrp + sub * 32);
        const float4 mb = *(const float4*)(mask + mgrp + sub * 32 + 4);
        *(uint2*)&vt[buf][dcol * 36 + ngrp * 8] =
            make_uint2(bfpk(vv[0] * ma.x, vv[1] * ma.y), bfpk(vv[2] * ma.z, vv[3] * ma.w));
        *(uint2*)&vt[buf][dcol * 36 + ngrp * 8 + 4] =
            make_uint2(bfpk(vv[4] * mb.x, vv[5] * mb.y), bfpk(vv[6] * mb.z, vv[7] * mb.w));
    };

    stage(0, 0);
    __syncthreads();

    for (int sub = 0; sub < 8; ++sub) {
        const int buf = sub & 1;
        if (sub < 7) stage(buf ^ 1, sub + 1);

        // ---- GEMM1: phi C-tile (A = K*m, 2xb64 LDS reads) ----
        f32x16 p = fz16();
#pragma unroll
        for (int ks = 0; ks < 4; ++ks) {
            const uint2 lo = *(const uint2*)&kt[buf][l31 * 68 + ks * 16 + hf * 8];
            const uint2 hi = *(const uint2*)&kt[buf][l31 * 68 + ks * 16 + hf * 8 + 4];
            S8U a; a.u = make_uint4(lo.x, lo.y, hi.x, hi.y);
            p = MFMA(a.s, pfrag[ks], p);
        }

        unsigned own[8];
#pragma unroll
        for (int g = 0; g < 4; ++g) {
            const float p0 = fmaxf(p[4*g+0], 0.f) + KEPS;
            const float p1 = fmaxf(p[4*g+1], 0.f) + KEPS;
            const float p2 = fmaxf(p[4*g+2], 0.f) + KEPS;
            const float p3 = fmaxf(p[4*g+3], 0.f) + KEPS;
            ksum += (p0 + p1) + (p2 + p3);
            own[2*g]   = bfpk(p0, p1);
            own[2*g+1] = bfpk(p2, p3);
        }
        unsigned par[8];
#pragma unroll
        for (int q = 0; q < 8; ++q) par[q] = (unsigned)__shfl_xor((int)own[q], 32, 64);

        // ---- GEMM2: ctxT += V^T . phi (A = vt, 2xb64 LDS reads) ----
#pragma unroll
        for (int kk = 0; kk < 2; ++kk) {
            S8U bf;
            if (hf == 0) bf.u = make_uint4(own[4*kk],   own[4*kk+1], par[4*kk],   par[4*kk+1]);
            else         bf.u = make_uint4(par[4*kk+2], par[4*kk+3], own[4*kk+2], own[4*kk+3]);
#pragma unroll
            for (int mt = 0; mt < 2; ++mt) {
                const int vbase = (mt * 32 + l31) * 36 + kk * 16 + hf * 8;
                const uint2 lo = *(const uint2*)&vt[buf][vbase];
                const uint2 hi = *(const uint2*)&vt[buf][vbase + 4];
                S8U av; av.u = make_uint4(lo.x, lo.y, hi.x, hi.y);
                acc[mt] = MFMA(av.s, bf.s, acc[mt]);
            }
        }
        __syncthreads();
    }

    // ---- epilogue: coalesced fp32 atomics into ctxT[bh][d][r] ----
#pragma unroll
    for (int mt = 0; mt < 2; ++mt)
#pragma unroll
        for (int i = 0; i < 16; ++i) {
            const int drow = mt * 32 + (i & 3) + 8 * (i >> 2) + 4 * hf;
            atomicAdd(g_ctxT + ((long)bh * DD + drow) * RR + rhalf * 128 + w * 32 + l31,
                      acc[mt][i]);
        }
    const float kst = ksum + __shfl_xor(ksum, 32, 64);
    if (hf == 0) atomicAdd(g_ksum + bh * RR + rhalf * 128 + w * 32 + l31, kst);
}

// ---------------------------------------------------------------------------
// Kernel 2: per (bh, n-chunk 128). Software-pipelined rt loop:
//   top:    issue raw ctxT loads for rt+1 (8 float4)
//   body:   GEMM3 (A = projb global, B = Q resident) -> phi -> s -> half-swap
//           GEMM4 (B = packed ctx frags from previous bottom)
//   bottom: pack rt+1 ctx fp32 -> bf16 (vmcnt drained by body's ~500 cyc)
// grid (32, HH, BB) = 1024 blocks; lb(256,3).
// ---------------------------------------------------------------------------
__global__ __launch_bounds__(256, 3)
void out_kernel(const float* __restrict__ Qmat, const unsigned short* __restrict__ projb,
                const float* __restrict__ g_ctxT, const float* __restrict__ g_ksum,
                float* __restrict__ out)
{
    __shared__ float ks_lds[RR];

    const int tid = threadIdx.x;
    const int w = tid >> 6, lane = tid & 63;
    const int l31 = lane & 31, hf = lane >> 5;
    const int bh = blockIdx.z * HH + blockIdx.y;
    const int n0 = blockIdx.x * 128;
    const int nl = w * 32 + l31;              // this lane's n (GEMM3 B col)

    ks_lds[tid] = g_ksum[bh * RR + tid];

    // resident Q B-frags (raw Q; SCALE lives in projb)
    const long qrow = ((long)bh * NN + n0 + nl) * DD;
    short8 qfr[4];
#pragma unroll
    for (int ks = 0; ks < 4; ++ks) {
        const float4 a = *(const float4*)(Qmat + qrow + ks * 16 + hf * 8);
        const float4 c = *(const float4*)(Qmat + qrow + ks * 16 + hf * 8 + 4);
        S8U t; t.u = make_uint4(bfpk(a.x, a.y), bfpk(a.z, a.w), bfpk(c.x, c.y), bfpk(c.z, c.w));
        qfr[ks] = t.s;
    }

    const float* ctxbase = g_ctxT + (long)bh * DD * RR + (long)l31 * RR;

    float4 nc[8];                             // raw prefetch: [kk*2+dt][lo/hi]
    auto load_ctx = [&](int rt) {
#pragma unroll
        for (int kk = 0; kk < 2; ++kk)
#pragma unroll
            for (int dt = 0; dt < 2; ++dt) {
                const float* cp = ctxbase + (long)dt * 32 * RR + rt * 32 + kk * 16 + hf * 8;
                nc[(kk * 2 + dt) * 2]     = *(const float4*)cp;
                nc[(kk * 2 + dt) * 2 + 1] = *(const float4*)(cp + 4);
            }
    };
    short8 cf[4];                             // packed ctx frags [kk*2+dt]
    auto pack_ctx = [&]() {
#pragma unroll
        for (int q = 0; q < 4; ++q) {
            const float4 x = nc[q * 2], y = nc[q * 2 + 1];
            S8U t; t.u = make_uint4(bfpk(x.x, x.y), bfpk(x.z, x.w),
                                    bfpk(y.x, y.y), bfpk(y.z, y.w));
            cf[q] = t.s;
        }
    };

    load_ctx(0);
    pack_ctx();
    __syncthreads();

    f32x16 cacc[2];
    cacc[0] = fz16(); cacc[1] = fz16();
    float s_acc = 0.f;

    for (int rt = 0; rt < 8; ++rt) {
        if (rt < 7) load_ctx(rt + 1);         // in flight across the body

        // ---- GEMM3 (A-frags from projb global/L1) ----
        f32x16 p = fz16();
#pragma unroll
        for (int ks = 0; ks < 4; ++ks) {
            const short8 af = *(const short8*)(projb + (rt * 32 + l31) * DD + ks * 16 + hf * 8);
            p = MFMA(af, qfr[ks], p);
        }
        // ---- epilogue: phi, s ----
        unsigned own[8];
#pragma unroll
        for (int g = 0; g < 4; ++g) {
            const float4 kv = *(const float4*)&ks_lds[rt * 32 + 8 * g + 4 * hf];
            const float p0 = fmaxf(p[4*g+0], 0.f) + KEPS; s_acc = fmaf(p0, kv.x, s_acc);
            const float p1 = fmaxf(p[4*g+1], 0.f) + KEPS; s_acc = fmaf(p1, kv.y, s_acc);
            const float p2 = fmaxf(p[4*g+2], 0.f) + KEPS; s_acc = fmaf(p2, kv.z, s_acc);
            const float p3 = fmaxf(p[4*g+3], 0.f) + KEPS; s_acc = fmaf(p3, kv.w, s_acc);
            own[2*g]   = bfpk(p0, p1);
            own[2*g+1] = bfpk(p2, p3);
        }
        unsigned par[8];
#pragma unroll
        for (int q = 0; q < 8; ++q) par[q] = (unsigned)__shfl_xor((int)own[q], 32, 64);

        // ---- GEMM4 (B = packed frags from previous bottom) ----
#pragma unroll
        for (int kk = 0; kk < 2; ++kk) {
            S8U a;
            if (hf == 0) a.u = make_uint4(own[4*kk],   own[4*kk+1], par[4*kk],   par[4*kk+1]);
            else         a.u = make_uint4(par[4*kk+2], par[4*kk+3], own[4*kk+2], own[4*kk+3]);
            cacc[0] = MFMA(a.s, cf[kk * 2 + 0], cacc[0]);
            cacc[1] = MFMA(a.s, cf[kk * 2 + 1], cacc[1]);
        }
        if (rt < 7) pack_ctx();               // bottom: vmcnt drained by body
    }

    const float st = s_acc + __shfl_xor(s_acc, 32, 64);
    const float sinv = 1.0f / st;             // valid at lane l31 = n-local-in-wave
#pragma unroll
    for (int i = 0; i < 16; ++i) {
        const int row = (i & 3) + 8 * (i >> 2) + 4 * hf;
        const float sv = __shfl(sinv, row, 64);
#pragma unroll
        for (int dt = 0; dt < 2; ++dt)
            out[((long)bh * NN + n0 + w * 32 + row) * DD + dt * 32 + l31] = cacc[dt][i] * sv;
    }
}

// ---------------------------------------------------------------------------
extern "C" void kernel_launch(void* const* d_in, const int* in_sizes, int n_in,
                              void* d_out, int out_size, void* d_ws, size_t ws_size,
                              hipStream_t stream)
{
    const float* Q    = (const float*)d_in[0];
    const float* K    = (const float*)d_in[1];
    const float* V    = (const float*)d_in[2];
    const float* mask = (const float*)d_in[3];
    const float* proj = (const float*)d_in[4];
    float* out = (float*)d_out;

    float* g_ctxT = (float*)d_ws;                               // BH*DD*RR fp32 (2 MB)
    float* g_ksum = g_ctxT + (size_t)BB * HH * DD * RR;         // BH*RR fp32 (32 KB)
    unsigned short* projb = (unsigned short*)(g_ksum + (size_t)BB * HH * RR);  // 32 KB

    const size_t zbytes = ((size_t)BB * HH * DD * RR + (size_t)BB * HH * RR) * sizeof(float);
    hipMemsetAsync(d_ws, 0, zbytes, stream);

    prep_proj<<<dim3(RR * DD / 1024), 256, 0, stream>>>(proj, projb);

    dim3 g1((NN / 256) * 2, HH, BB);   // 1024 blocks
    pk_ctx_kernel<<<g1, 256, 0, stream>>>(K, V, mask, projb, g_ctxT, g_ksum);

    dim3 g2(NN / 128, HH, BB);         // 1024 blocks
    out_kernel<<<g2, 256, 0, stream>>>(Q, projb, g_ctxT, g_ksum, out);
}

// Round 8
// 180.016 us; speedup vs baseline: 1.4198x; 1.4198x over previous
//
#include <hip/hip_runtime.h>
#include <hip/hip_bf16.h>

#define BB 4
#define HH 8
#define NN 4096
#define DD 64
#define RR 256

constexpr float SCALE = 0.35355339059327373f;  // 64^(-1/4)
constexpr float KEPS  = 0.001f;

typedef __attribute__((ext_vector_type(8)))  short short8;   // MFMA A/B frag
typedef __attribute__((ext_vector_type(16))) float f32x16;   // 32x32 MFMA C/D

#define MFMA(a, b, c) __builtin_amdgcn_mfma_f32_32x32x16_bf16(a, b, c, 0, 0, 0)

union S8U { short8 s; uint4 u; };

__device__ inline unsigned bfpk(float a, float b) {          // fp32x2 -> bf16x2 RTNE
    __hip_bfloat162 h = __float22bfloat162_rn(make_float2(a, b));
    return *reinterpret_cast<unsigned*>(&h);
}
__device__ inline f32x16 fz16() {
    f32x16 z;
#pragma unroll
    for (int e = 0; e < 16; ++e) z[e] = 0.f;
    return z;
}

// ---------------------------------------------------------------------------
// prep: projb = bf16(proj * SCALE)  row-major [256][64]
// ---------------------------------------------------------------------------
__global__ __launch_bounds__(256)
void prep_proj(const float* __restrict__ proj, unsigned short* __restrict__ projb)
{
    const int i = (blockIdx.x * 256 + threadIdx.x) * 4;
    const float4 v = *(const float4*)(proj + i);
    uint2 o; o.x = bfpk(v.x * SCALE, v.y * SCALE); o.y = bfpk(v.z * SCALE, v.w * SCALE);
    *(uint2*)(projb + i) = o;
}

// ---------------------------------------------------------------------------
// Kernel 1 (unchanged from round 7): per (bh, n-chunk 256, r-half 128).
// Double-buffered LDS staging (K*m row-major / V^T*m transposed), register
// half-swap phi, GEMM2 into ctxT[bh][d][r], coalesced fp32 atomics.
// ---------------------------------------------------------------------------
__global__ __launch_bounds__(256, 3)
void pk_ctx_kernel(const float* __restrict__ Kmat, const float* __restrict__ Vmat,
                   const float* __restrict__ mask, const unsigned short* __restrict__ projb,
                   float* __restrict__ g_ctxT, float* __restrict__ g_ksum)
{
    __shared__ __align__(16) unsigned short kt[2][32 * 68];   // 8.5 KB
    __shared__ __align__(16) unsigned short vt[2][64 * 36];   // 9 KB

    const int tid = threadIdx.x;
    const int w = tid >> 6, lane = tid & 63;
    const int l31 = lane & 31, hf = lane >> 5;
    const int b = blockIdx.z, h = blockIdx.y;
    const int bh = b * HH + h;
    const int nc = blockIdx.x >> 1, rhalf = blockIdx.x & 1;
    const int n0 = nc * 256;
    const int rg = rhalf * 128 + w * 32 + l31;         // this lane's r

    const int sn = tid >> 3, sc = (tid & 7) * 8;
    const long krow = ((long)bh * NN + n0 + sn) * DD + sc;
    const int  mrow = b * NN + n0 + sn;
    const int dcol = tid & 63, ngrp = tid >> 6;
    const long vcol = ((long)bh * NN + n0 + ngrp * 8) * DD + dcol;
    const int  mgrp = b * NN + n0 + ngrp * 8;

    short8 pfrag[4];
#pragma unroll
    for (int ks = 0; ks < 4; ++ks)
        pfrag[ks] = *(const short8*)(projb + rg * DD + ks * 16 + hf * 8);

    f32x16 acc[2];
    acc[0] = fz16(); acc[1] = fz16();
    float ksum = 0.f;

    auto stage = [&](int buf, int sub) {
        const long koff = krow + (long)sub * 32 * DD;
        const float m = mask[mrow + sub * 32];
        const float4 ka = *(const float4*)(Kmat + koff);
        const float4 kc = *(const float4*)(Kmat + koff + 4);
        *(uint2*)&kt[buf][sn * 68 + sc] =
            make_uint2(bfpk(ka.x * m, ka.y * m), bfpk(ka.z * m, ka.w * m));
        *(uint2*)&kt[buf][sn * 68 + sc + 4] =
            make_uint2(bfpk(kc.x * m, kc.y * m), bfpk(kc.z * m, kc.w * m));
        const long voff = vcol + (long)sub * 32 * DD;
        float vv[8];
#pragma unroll
        for (int j = 0; j < 8; ++j) vv[j] = Vmat[voff + (long)j * DD];
        const float4 ma = *(const float4*)(mask + mgrp + sub * 32);
        const float4 mb = *(const float4*)(mask + mgrp + sub * 32 + 4);
        *(uint2*)&vt[buf][dcol * 36 + ngrp * 8] =
            make_uint2(bfpk(vv[0] * ma.x, vv[1] * ma.y), bfpk(vv[2] * ma.z, vv[3] * ma.w));
        *(uint2*)&vt[buf][dcol * 36 + ngrp * 8 + 4] =
            make_uint2(bfpk(vv[4] * mb.x, vv[5] * mb.y), bfpk(vv[6] * mb.z, vv[7] * mb.w));
    };

    stage(0, 0);
    __syncthreads();

    for (int sub = 0; sub < 8; ++sub) {
        const int buf = sub & 1;
        if (sub < 7) stage(buf ^ 1, sub + 1);

        f32x16 p = fz16();
#pragma unroll
        for (int ks = 0; ks < 4; ++ks) {
            const uint2 lo = *(const uint2*)&kt[buf][l31 * 68 + ks * 16 + hf * 8];
            const uint2 hi = *(const uint2*)&kt[buf][l31 * 68 + ks * 16 + hf * 8 + 4];
            S8U a; a.u = make_uint4(lo.x, lo.y, hi.x, hi.y);
            p = MFMA(a.s, pfrag[ks], p);
        }

        unsigned own[8];
#pragma unroll
        for (int g = 0; g < 4; ++g) {
            const float p0 = fmaxf(p[4*g+0], 0.f) + KEPS;
            const float p1 = fmaxf(p[4*g+1], 0.f) + KEPS;
            const float p2 = fmaxf(p[4*g+2], 0.f) + KEPS;
            const float p3 = fmaxf(p[4*g+3], 0.f) + KEPS;
            ksum += (p0 + p1) + (p2 + p3);
            own[2*g]   = bfpk(p0, p1);
            own[2*g+1] = bfpk(p2, p3);
        }
        unsigned par[8];
#pragma unroll
        for (int q = 0; q < 8; ++q) par[q] = (unsigned)__shfl_xor((int)own[q], 32, 64);

#pragma unroll
        for (int kk = 0; kk < 2; ++kk) {
            S8U bf;
            if (hf == 0) bf.u = make_uint4(own[4*kk],   own[4*kk+1], par[4*kk],   par[4*kk+1]);
            else         bf.u = make_uint4(par[4*kk+2], par[4*kk+3], own[4*kk+2], own[4*kk+3]);
#pragma unroll
            for (int mt = 0; mt < 2; ++mt) {
                const int vbase = (mt * 32 + l31) * 36 + kk * 16 + hf * 8;
                const uint2 lo = *(const uint2*)&vt[buf][vbase];
                const uint2 hi = *(const uint2*)&vt[buf][vbase + 4];
                S8U av; av.u = make_uint4(lo.x, lo.y, hi.x, hi.y);
                acc[mt] = MFMA(av.s, bf.s, acc[mt]);
            }
        }
        __syncthreads();
    }

#pragma unroll
    for (int mt = 0; mt < 2; ++mt)
#pragma unroll
        for (int i = 0; i < 16; ++i) {
            const int drow = mt * 32 + (i & 3) + 8 * (i >> 2) + 4 * hf;
            atomicAdd(g_ctxT + ((long)bh * DD + drow) * RR + rhalf * 128 + w * 32 + l31,
                      acc[mt][i]);
        }
    const float kst = ksum + __shfl_xor(ksum, 32, 64);
    if (hf == 0) atomicAdd(g_ksum + bh * RR + rhalf * 128 + w * 32 + l31, kst);
}

// ---------------------------------------------------------------------------
// Kernel 2 (rewritten): per (bh, n-chunk 256), block = 512 threads (8 waves).
// Stage ONCE (coalesced): proj bf16 -> pl[256][68], ctxT fp32 -> bf16
// ctl[64][260], ksum -> ksl. Then a ZERO-BARRIER rt loop: all fragment reads
// are LDS 2xb64 (stride-68 pattern, measured conflict-free in r7 pk_ctx).
//   GEMM3: C3[r][n] (A = pl, B = Q resident)   col = n = l31
//   epilogue: phi = relu+eps; s += phi*ksum; half-swap -> A-frags
//   GEMM4: cacc[n][d] += phi . ctx (B = ctl [d][r], k = r)
// Output: cacc -> LDS (overlay on pl) -> coalesced float4 stores, 2 halves.
// grid (16, HH, BB) = 512 blocks = exactly 2/CU; lb(512,4) caps 128 regs.
// ---------------------------------------------------------------------------
#define PL_STRIDE  68
#define CTL_STRIDE 260
#define OB_STRIDE  68

__global__ __launch_bounds__(512, 4)
void out_kernel(const float* __restrict__ Qmat, const unsigned short* __restrict__ projb,
                const float* __restrict__ g_ctxT, const float* __restrict__ g_ksum,
                float* __restrict__ out)
{
    __shared__ __align__(16) char smem[34816 + 33280 + 1024];
    unsigned short* pl  = (unsigned short*)smem;             // [256][68] proj
    unsigned short* ctl = (unsigned short*)(smem + 34816);   // [64][260] ctx bf16
    float*          ksl = (float*)(smem + 34816 + 33280);    // [256]
    float*          ob  = (float*)smem;                      // out overlay [128][68]

    const int tid = threadIdx.x;
    const int w = tid >> 6, lane = tid & 63;
    const int l31 = lane & 31, hf = lane >> 5;
    const int bh = blockIdx.z * HH + blockIdx.y;
    const int n0 = blockIdx.x * 256;
    const int nl = w * 32 + l31;              // n-local 0..255 (GEMM3 B col)

    // ---- stage proj (coalesced uint4): 2048 uint4, 4/thread ----
#pragma unroll
    for (int it = 0; it < 4; ++it) {
        const int u = tid + it * 512;
        const uint4 v = ((const uint4*)projb)[u];
        *(uint4*)&pl[(u >> 3) * PL_STRIDE + (u & 7) * 8] = v;
    }
    // ---- stage ctx (coalesced float4 -> bf16): 4096 float4, 8/thread ----
    {
        const float* cb = g_ctxT + (long)bh * DD * RR;
#pragma unroll
        for (int it = 0; it < 8; ++it) {
            const int f = tid + it * 512;           // float4 index
            const int d = f >> 6, rq = (f & 63) * 4;
            const float4 v = ((const float4*)cb)[f];
            *(uint2*)&ctl[d * CTL_STRIDE + rq] = make_uint2(bfpk(v.x, v.y), bfpk(v.z, v.w));
        }
    }
    if (tid < 256) ksl[tid] = g_ksum[bh * RR + tid];

    // ---- resident Q B-frags (raw Q; SCALE lives in projb) ----
    const long qrow = ((long)bh * NN + n0 + nl) * DD;
    short8 qfr[4];
#pragma unroll
    for (int ks = 0; ks < 4; ++ks) {
        const float4 a = *(const float4*)(Qmat + qrow + ks * 16 + hf * 8);
        const float4 c = *(const float4*)(Qmat + qrow + ks * 16 + hf * 8 + 4);
        S8U t; t.u = make_uint4(bfpk(a.x, a.y), bfpk(a.z, a.w), bfpk(c.x, c.y), bfpk(c.z, c.w));
        qfr[ks] = t.s;
    }
    __syncthreads();

    f32x16 cacc[2];
    cacc[0] = fz16(); cacc[1] = fz16();
    float s_acc = 0.f;

    for (int rt = 0; rt < 8; ++rt) {          // zero barriers inside
        // ---- GEMM3: A from pl (2xb64, conflict-free) ----
        f32x16 p = fz16();
#pragma unroll
        for (int ks = 0; ks < 4; ++ks) {
            const int ab = (rt * 32 + l31) * PL_STRIDE + ks * 16 + hf * 8;
            const uint2 lo = *(const uint2*)&pl[ab];
            const uint2 hi = *(const uint2*)&pl[ab + 4];
            S8U a; a.u = make_uint4(lo.x, lo.y, hi.x, hi.y);
            p = MFMA(a.s, qfr[ks], p);
        }
        // ---- epilogue: phi, s ----
        unsigned own[8];
#pragma unroll
        for (int g = 0; g < 4; ++g) {
            const float4 kv = *(const float4*)&ksl[rt * 32 + 8 * g + 4 * hf];
            const float p0 = fmaxf(p[4*g+0], 0.f) + KEPS; s_acc = fmaf(p0, kv.x, s_acc);
            const float p1 = fmaxf(p[4*g+1], 0.f) + KEPS; s_acc = fmaf(p1, kv.y, s_acc);
            const float p2 = fmaxf(p[4*g+2], 0.f) + KEPS; s_acc = fmaf(p2, kv.z, s_acc);
            const float p3 = fmaxf(p[4*g+3], 0.f) + KEPS; s_acc = fmaf(p3, kv.w, s_acc);
            own[2*g]   = bfpk(p0, p1);
            own[2*g+1] = bfpk(p2, p3);
        }
        unsigned par[8];
#pragma unroll
        for (int q = 0; q < 8; ++q) par[q] = (unsigned)__shfl_xor((int)own[q], 32, 64);

        // ---- GEMM4: B from ctl (2xb64, conflict-free) ----
#pragma unroll
        for (int kk = 0; kk < 2; ++kk) {
            S8U a;
            if (hf == 0) a.u = make_uint4(own[4*kk],   own[4*kk+1], par[4*kk],   par[4*kk+1]);
            else         a.u = make_uint4(par[4*kk+2], par[4*kk+3], own[4*kk+2], own[4*kk+3]);
#pragma unroll
            for (int dt = 0; dt < 2; ++dt) {
                const int cb2 = (dt * 32 + l31) * CTL_STRIDE + rt * 32 + kk * 16 + hf * 8;
                const uint2 lo = *(const uint2*)&ctl[cb2];
                const uint2 hi = *(const uint2*)&ctl[cb2 + 4];
                S8U bfr; bfr.u = make_uint4(lo.x, lo.y, hi.x, hi.y);
                cacc[dt] = MFMA(a.s, bfr.s, cacc[dt]);
            }
        }
    }

    // ---- s, then LDS-staged coalesced output (2 halves of 128 n) ----
    const float st = s_acc + __shfl_xor(s_acc, 32, 64);
    const float sinv = 1.0f / st;             // valid at lane l31 = n-local-in-wave

    for (int half = 0; half < 2; ++half) {
        __syncthreads();                      // ob overlay free (pl / prev half done)
        if ((w >> 2) == half) {
#pragma unroll
            for (int i = 0; i < 16; ++i) {
                const int row = (i & 3) + 8 * (i >> 2) + 4 * hf;
                const float sv = __shfl(sinv, row, 64);
                const int rloc = (w & 3) * 32 + row;
#pragma unroll
                for (int dt = 0; dt < 2; ++dt)
                    ob[rloc * OB_STRIDE + dt * 32 + l31] = cacc[dt][i] * sv;
            }
        }
        __syncthreads();
#pragma unroll
        for (int it = 0; it < 4; ++it) {
            const int f = tid + it * 512;     // 0..2047 float4 over 128 rows x 64 d
            const int row = f >> 4, dq = (f & 15) * 4;
            const float* src = &ob[row * OB_STRIDE + dq];
            const float4 v = make_float4(src[0], src[1], src[2], src[3]);
            *(float4*)(out + ((long)bh * NN + n0 + half * 128 + row) * DD + dq) = v;
        }
    }
}

// ---------------------------------------------------------------------------
extern "C" void kernel_launch(void* const* d_in, const int* in_sizes, int n_in,
                              void* d_out, int out_size, void* d_ws, size_t ws_size,
                              hipStream_t stream)
{
    const float* Q    = (const float*)d_in[0];
    const float* K    = (const float*)d_in[1];
    const float* V    = (const float*)d_in[2];
    const float* mask = (const float*)d_in[3];
    const float* proj = (const float*)d_in[4];
    float* out = (float*)d_out;

    float* g_ctxT = (float*)d_ws;                               // BH*DD*RR fp32 (2 MB)
    float* g_ksum = g_ctxT + (size_t)BB * HH * DD * RR;         // BH*RR fp32 (32 KB)
    unsigned short* projb = (unsigned short*)(g_ksum + (size_t)BB * HH * RR);  // 32 KB

    const size_t zbytes = ((size_t)BB * HH * DD * RR + (size_t)BB * HH * RR) * sizeof(float);
    hipMemsetAsync(d_ws, 0, zbytes, stream);

    prep_proj<<<dim3(RR * DD / 1024), 256, 0, stream>>>(proj, projb);

    dim3 g1((NN / 256) * 2, HH, BB);   // 1024 blocks
    pk_ctx_kernel<<<g1, 256, 0, stream>>>(K, V, mask, projb, g_ctxT, g_ksum);

    dim3 g2(NN / 256, HH, BB);         // 512 blocks, 512 threads
    out_kernel<<<g2, 512, 0, stream>>>(Q, projb, g_ctxT, g_ksum, out);
}